// Round 9
// baseline (378.557 us; speedup 1.0000x reference)
//
#include <hip/hip_runtime.h>

#define NREL 8
#define NNODE 100000
#define TNODE 50000
#define NEDGE 800000
#define C 128
#define TILE_T 64
#define NTILE ((TNODE + TILE_T - 1) / TILE_T)   // 782
#define NENT (NREL * TNODE)                     // 400000 scatter entries
#define NB_SCAN ((NNODE + 255) / 256)           // 391

typedef unsigned int u32;
typedef unsigned short u16;
typedef __attribute__((ext_vector_type(8))) short bf16x8;
typedef __attribute__((ext_vector_type(4))) float f32x4;
typedef __attribute__((ext_vector_type(2))) float f32x2;

__device__ __forceinline__ float bf2f(u16 h) {
    union { u32 u; float f; } c; c.u = ((u32)h) << 16; return c.f;
}
__device__ __forceinline__ u16 f2bf(float f) {
    union { float f; u32 u; } c; c.f = f;
    u32 u = c.u + 0x7FFFu + ((c.u >> 16) & 1u);   // RNE
    return (u16)(u >> 16);
}
__device__ __forceinline__ u32 pack2(float a, float b) {
    return (u32)f2bf(a) | ((u32)f2bf(b) << 16);
}
__device__ __forceinline__ float2 unpack_bf2(u32 p) {
    union { u32 u; float f; } a, b;
    a.u = p << 16; b.u = p & 0xFFFF0000u;
    return make_float2(a.f, b.f);
}
__device__ __forceinline__ f32x2 bits2(u32 p) {
    union { u32 u[2]; f32x2 f; } c;
    c.u[0] = p << 16; c.u[1] = p & 0xFFFF0000u;
    return c.f;
}
__device__ __forceinline__ void addp(f32x2* a, uint4 v) {   // 8 bf16 cols -> 4 pk-adds
    a[0] += bits2(v.x); a[1] += bits2(v.y);
    a[2] += bits2(v.z); a[3] += bits2(v.w);
}
__device__ __forceinline__ void fma4(float4& acc, float a, float w0, float w1, float w2, float w3) {
    acc.x = fmaf(a, w0, acc.x);
    acc.y = fmaf(a, w1, acc.y);
    acc.z = fmaf(a, w2, acc.z);
    acc.w = fmaf(a, w3, acc.w);
}

// ---------------- kernel 1a: x f32 -> bf16 ----------------
__global__ __launch_bounds__(256)
void convert_x_kernel(const float* __restrict__ x, u16* __restrict__ xb, int n4) {
    int i = blockIdx.x * 256 + threadIdx.x;
    const int stride = gridDim.x * 256;
    for (; i < n4; i += stride) {
        const float4 v = ((const float4*)x)[i];
        ushort4 o;
        o.x = f2bf(v.x); o.y = f2bf(v.y); o.z = f2bf(v.z); o.w = f2bf(v.w);
        ((ushort4*)xb)[i] = o;
    }
}

// ---------------- kernel 1b: W f32 [r][k][c] -> bf16 W^T [r][c][k] ----------------
__global__ __launch_bounds__(256)
void convert_w_kernel(const float* __restrict__ w, u16* __restrict__ wtb) {
    const int o = blockIdx.x * 256 + threadIdx.x;   // enumerates (r, c, k), k inner
    if (o < NREL * C * C) {
        const int r = o >> 14, rem = o & 16383, cc = rem >> 7, k = rem & 127;
        wtb[o] = f2bf(w[(r << 14) + k * C + cc]);
    }
}

// ---------------- inverted-index build ----------------
__global__ __launch_bounds__(256)
void hist_kernel(const int* __restrict__ tgt, int* __restrict__ count) {
    const int g = blockIdx.x * 256 + threadIdx.x;
    if (g < NENT) atomicAdd(&count[tgt[g]], 1);
}

__global__ __launch_bounds__(256)
void scan1_kernel(const int* __restrict__ count, int* __restrict__ bsum) {
    __shared__ int s[256];
    const int tid = threadIdx.x;
    const int i = blockIdx.x * 256 + tid;
    s[tid] = (i < NNODE) ? count[i] : 0;
    __syncthreads();
    for (int st = 128; st > 0; st >>= 1) {
        if (tid < st) s[tid] += s[tid + st];
        __syncthreads();
    }
    if (tid == 0) bsum[blockIdx.x] = s[0];
}

__global__ __launch_bounds__(512)
void scan2_kernel(int* __restrict__ bsum) {   // 1 block, exclusive scan of NB_SCAN partials
    __shared__ int s[512];
    const int tid = threadIdx.x;
    const int v = (tid < NB_SCAN) ? bsum[tid] : 0;
    s[tid] = v;
    __syncthreads();
    for (int st = 1; st < 512; st <<= 1) {
        const int t = (tid >= st) ? s[tid - st] : 0;
        __syncthreads();
        s[tid] += t;
        __syncthreads();
    }
    if (tid < NB_SCAN) bsum[tid] = s[tid] - v;   // exclusive
}

__global__ __launch_bounds__(256)
void scan3_kernel(const int* __restrict__ count, const int* __restrict__ bsum,
                  int* __restrict__ offsets, int* __restrict__ cursor) {
    __shared__ int s[256];
    const int tid = threadIdx.x;
    const int i = blockIdx.x * 256 + tid;
    const int v = (i < NNODE) ? count[i] : 0;
    s[tid] = v;
    __syncthreads();
    for (int st = 1; st < 256; st <<= 1) {
        const int t = (tid >= st) ? s[tid - st] : 0;
        __syncthreads();
        s[tid] += t;
        __syncthreads();
    }
    if (i < NNODE) {
        const int off = bsum[blockIdx.x] + s[tid] - v;   // exclusive prefix
        offsets[i] = off;
        cursor[i]  = off;
    }
}

__global__ __launch_bounds__(256)
void fill_kernel(const int* __restrict__ tgt, int* __restrict__ cursor, int* __restrict__ list) {
    const int g = blockIdx.x * 256 + threadIdx.x;
    if (g < NENT) {
        const int pos = atomicAdd(&cursor[tgt[g]], 1);
        list[pos] = g;
    }
}

// ---------------- kernel 2: FUSED gather-sum + MFMA GEMM -> P(=arr) ----------------
// Block = (64-target tile, relation r). 8 waves x 64 lanes.
// Phase 1: each 16-lane QUARTER-WAVE owns one target (popped from LDS ticket
//          queue). Lane c accumulates cols [c*8, c*8+8) over the whole segment:
//          no cross-lane fold, no index shuffle, 4 independent chains/wave.
// Phase 2: MFMA GEMM sA @ sB(W^T) -> P rows (bf16), via LDS repack.
__global__ __launch_bounds__(512, 6)
void fused_gather_gemm_kernel(const u16* __restrict__ xb, const int* __restrict__ ptr,
                              const int* __restrict__ idx, const u16* __restrict__ wtb,
                              u16* __restrict__ P) {
    __shared__ u16 sB[C * 136];        // 34816 B: W^T [col][k+pad]
    __shared__ u16 sA[TILE_T * 136];   // 17408 B: agg tile -> output tile
    __shared__ int qcount;             // dynamic target ticket

    const int tid  = threadIdx.x;
    const int tile = blockIdx.x;
    const int r    = blockIdx.y;
    const int w    = tid >> 6;
    const int lane = tid & 63;

    // ---- stage W^T into sB (overlaps gather; pre-GEMM barrier covers it) ----
    {
        const uint4* src = (const uint4*)(wtb + (size_t)r * C * C);
        #pragma unroll
        for (int i = 0; i < 4; ++i) {
            const int f = tid + i * 512;        // 2048 16B-units
            const int col = f >> 4, unit = f & 15;
            *(uint4*)(sB + col * 136 + unit * 8) = src[f];
        }
    }
    if (tid == 0) qcount = 0;
    __syncthreads();   // qcount visible to all waves

    // ---- phase 1: quarter-wave per target, dynamic ticket ----
    const int* pr = ptr + r * (TNODE + 1);
    const int* er = idx + (size_t)r * NEDGE;
    const int c  = lane & 15;            // 8-col chunk (16B) owned by this lane
    const u16* xq = xb + c * 8;

    for (;;) {
        int tl;
        if (c == 0) tl = atomicAdd(&qcount, 1);
        tl = __shfl(tl, lane & 48);      // broadcast from quarter leader
        if (tl >= TILE_T) break;

        const int t = tile * TILE_T + tl;
        f32x2 a0[4], a1[4];
        #pragma unroll
        for (int j = 0; j < 4; ++j) { a0[j] = (f32x2){0.f, 0.f}; a1[j] = (f32x2){0.f, 0.f}; }

        if (t < TNODE) {
            // clip(searchsorted(ptr,e,'right')-1, 0, T-1):
            //   t==0 owns [0, ptr[1]); t==T-1 owns [ptr[T-1], E)
            int s           = (t == 0) ? 0 : pr[t];
            const int e1    = (t == TNODE - 1) ? NEDGE : pr[t + 1];

            for (; s + 4 <= e1; s += 4) {     // 4 rows in flight per quarter
                const int i0 = er[s], i1 = er[s + 1], i2 = er[s + 2], i3 = er[s + 3];
                const uint4 v0 = *(const uint4*)(xq + (size_t)i0 * C);
                const uint4 v1 = *(const uint4*)(xq + (size_t)i1 * C);
                const uint4 v2 = *(const uint4*)(xq + (size_t)i2 * C);
                const uint4 v3 = *(const uint4*)(xq + (size_t)i3 * C);
                addp(a0, v0); addp(a1, v1);
                addp(a0, v2); addp(a1, v3);
            }
            for (; s < e1; ++s) {             // 0..3 leftover edges
                const int i0 = er[s];
                const uint4 v0 = *(const uint4*)(xq + (size_t)i0 * C);
                addp(a0, v0);
            }
        }
        #pragma unroll
        for (int j = 0; j < 4; ++j) a0[j] += a1[j];

        // 16 lanes write the full 256B row (zeros for t >= TNODE); no fold needed
        uint4 o;
        o.x = pack2(a0[0].x, a0[0].y);
        o.y = pack2(a0[1].x, a0[1].y);
        o.z = pack2(a0[2].x, a0[2].y);
        o.w = pack2(a0[3].x, a0[3].y);
        *(uint4*)(sA + tl * 136 + c * 8) = o;
    }
    __syncthreads();

    // ---- phase 2: MFMA GEMM. wave w: rows (w&3)*16..+16, col-block (w>>2)*64..+64 ----
    const int wr    = (w & 3) * 16;
    const int cbase = (w >> 2) * 4;      // cf offset (cf = 16-col block)
    const int fr    = lane & 15;
    const int fq    = lane >> 4;

    f32x4 acc[4];
    #pragma unroll
    for (int cf = 0; cf < 4; ++cf) acc[cf] = (f32x4){0.f, 0.f, 0.f, 0.f};

    #pragma unroll
    for (int ks = 0; ks < 4; ++ks) {
        const bf16x8 a = *(const bf16x8*)(sA + (wr + fr) * 136 + ks * 32 + fq * 8);
        #pragma unroll
        for (int cf = 0; cf < 4; ++cf) {
            const bf16x8 b = *(const bf16x8*)(sB + ((cbase + cf) * 16 + fr) * 136 + ks * 32 + fq * 8);
            acc[cf] = __builtin_amdgcn_mfma_f32_16x16x32_bf16(a, b, acc[cf], 0, 0, 0);
        }
    }
    __syncthreads();   // all A-frag reads done before D overwrites sA

    // D -> sA as bf16 (C/D layout: col=lane&15, row=(lane>>4)*4+reg)
    #pragma unroll
    for (int cf = 0; cf < 4; ++cf) {
        #pragma unroll
        for (int j = 0; j < 4; ++j) {
            const int row = wr + fq * 4 + j;
            sA[row * 136 + (cbase + cf) * 16 + fr] = f2bf(acc[cf][j]);
        }
    }
    __syncthreads();

    // coalesced store into P
    #pragma unroll
    for (int i = 0; i < 2; ++i) {
        const int f = tid + i * 512;        // 1024 16B-units
        const int row = f >> 4, unit = f & 15;
        const int t = tile * TILE_T + row;
        if (t < TNODE)
            *(uint4*)(P + ((size_t)r * TNODE + t) * C + unit * 8) =
                *(const uint4*)(sA + row * 136 + unit * 8);
    }
}

// ---------------- kernel 3: per-node gather of bf16 arr rows (no atomics) ----------------
__global__ __launch_bounds__(256)
void out_gather_kernel(const u16* __restrict__ P, const int* __restrict__ offsets,
                       const int* __restrict__ count, const int* __restrict__ list,
                       float* __restrict__ out) {
    const int lane = threadIdx.x & 63;
    const int n = blockIdx.x * 4 + (threadIdx.x >> 6);
    if (n >= NNODE) return;
    const int st = offsets[n];
    const int en = st + count[n];
    float2 a0 = make_float2(0.f, 0.f), a1 = make_float2(0.f, 0.f);
    int i = st;
    for (; i + 2 <= en; i += 2) {
        const u32 v0 = ((const u32*)(P + (size_t)list[i] * C))[lane];
        const u32 v1 = ((const u32*)(P + (size_t)list[i + 1] * C))[lane];
        const float2 f0 = unpack_bf2(v0), f1 = unpack_bf2(v1);
        a0.x += f0.x; a0.y += f0.y;
        a1.x += f1.x; a1.y += f1.y;
    }
    if (i < en) {
        const float2 f0 = unpack_bf2(((const u32*)(P + (size_t)list[i] * C))[lane]);
        a0.x += f0.x; a0.y += f0.y;
    }
    a0.x += a1.x; a0.y += a1.y;
    ((float2*)(out + (size_t)n * C))[lane] = a0;
}

// ---------------- fallback: round-1 fused kernel (used only if ws too small) ----------------
__device__ __forceinline__ void add4(float4& acc, const float4& b) {
    acc.x += b.x; acc.y += b.y; acc.z += b.z; acc.w += b.w;
}
__global__ __launch_bounds__(256, 1)
void rgcn_fused_kernel(const float* __restrict__ x, const float* __restrict__ w,
                       const int* __restrict__ ptr, const int* __restrict__ idx,
                       const int* __restrict__ tgt, float* __restrict__ out) {
    __shared__ float sW[C * C];
    __shared__ float sAgg[TILE_T][C + 4];
    const int tid = threadIdx.x, tile = blockIdx.x, r = blockIdx.y;
    {
        const float4* src = (const float4*)(w + (size_t)r * C * C);
        float4* dst = (float4*)sW;
        #pragma unroll
        for (int i = 0; i < 16; ++i) dst[tid + i * 256] = src[tid + i * 256];
    }
    {
        const int tl = tid >> 2, g = tid & 3;
        const int t = tile * TILE_T + tl;
        float4 a[8];
        #pragma unroll
        for (int j = 0; j < 8; ++j) a[j] = make_float4(0.f, 0.f, 0.f, 0.f);
        if (t < TNODE) {
            const int* pr = ptr + (size_t)r * (TNODE + 1);
            const int* er = idx + (size_t)r * NEDGE;
            int e = (t == 0) ? 0 : pr[t];
            const int end = (t == TNODE - 1) ? NEDGE : pr[t + 1];
            for (; e < end; ++e) {
                const int s0 = er[e];
                const float4* r0 = (const float4*)(x + (size_t)s0 * C) + g * 8;
                #pragma unroll
                for (int j = 0; j < 8; ++j) add4(a[j], r0[j]);
            }
        }
        float* rowp = &sAgg[tl][g * 32];
        #pragma unroll
        for (int j = 0; j < 8; ++j) ((float4*)rowp)[j] = a[j];
    }
    __syncthreads();
    const int tg = tid >> 4, cg = tid & 15;
    float4 acc0[4], acc1[4];
    #pragma unroll
    for (int i = 0; i < 4; ++i) {
        acc0[i] = make_float4(0.f, 0.f, 0.f, 0.f);
        acc1[i] = make_float4(0.f, 0.f, 0.f, 0.f);
    }
    for (int k4 = 0; k4 < C / 4; ++k4) {
        float4 av[4];
        #pragma unroll
        for (int i = 0; i < 4; ++i) av[i] = *(const float4*)&sAgg[tg * 4 + i][k4 * 4];
        #pragma unroll
        for (int kk = 0; kk < 4; ++kk) {
            const int k = k4 * 4 + kk;
            const float4 w0 = *(const float4*)&sW[k * C + cg * 4];
            const float4 w1 = *(const float4*)&sW[k * C + 64 + cg * 4];
            #pragma unroll
            for (int i = 0; i < 4; ++i) {
                const float a = ((const float*)&av[i])[kk];
                fma4(acc0[i], a, w0.x, w0.y, w0.z, w0.w);
                fma4(acc1[i], a, w1.x, w1.y, w1.z, w1.w);
            }
        }
    }
    const int* tr = tgt + (size_t)r * TNODE;
    #pragma unroll
    for (int i = 0; i < 4; ++i) {
        const int t = tile * TILE_T + tg * 4 + i;
        if (t < TNODE) {
            const int node = tr[t];
            float* ob = out + (size_t)node * C + cg * 4;
            unsafeAtomicAdd(ob + 0, acc0[i].x);  unsafeAtomicAdd(ob + 1, acc0[i].y);
            unsafeAtomicAdd(ob + 2, acc0[i].z);  unsafeAtomicAdd(ob + 3, acc0[i].w);
            unsafeAtomicAdd(ob + 64, acc1[i].x); unsafeAtomicAdd(ob + 65, acc1[i].y);
            unsafeAtomicAdd(ob + 66, acc1[i].z); unsafeAtomicAdd(ob + 67, acc1[i].w);
        }
    }
}

extern "C" void kernel_launch(void* const* d_in, const int* in_sizes, int n_in,
                              void* d_out, int out_size, void* d_ws, size_t ws_size,
                              hipStream_t stream) {
    const float* x   = (const float*)d_in[0];
    const float* w   = (const float*)d_in[1];
    const int*   ptr = (const int*)d_in[2];
    const int*   idx = (const int*)d_in[3];
    const int*   tgt = (const int*)d_in[4];
    float* out = (float*)d_out;

    // workspace layout (all offsets 16B-aligned)
    const size_t P_OFF    = 0;                     // 400000*128*2 = 102,400,000
    const size_t XB_OFF   = 104000000;             // 25,600,000
    const size_t WTB_OFF  = 130000000;             //    262,144
    const size_t CNT_OFF  = 131000000;             //    400,000
    const size_t OFFS_OFF = 131500000;
    const size_t CUR_OFF  = 132000000;
    const size_t BSUM_OFF = 132500000;
    const size_t LIST_OFF = 133000000;             //  1,600,000 -> ends 134.6 MB
    const size_t WS_NEED  = 135000000;

    if (ws_size >= WS_NEED) {
        char* base = (char*)d_ws;
        u16*   P       = (u16*)(base + P_OFF);
        u16*   xb      = (u16*)(base + XB_OFF);
        u16*   wtb     = (u16*)(base + WTB_OFF);
        int*   count   = (int*)(base + CNT_OFF);
        int*   offsets = (int*)(base + OFFS_OFF);
        int*   cursor  = (int*)(base + CUR_OFF);
        int*   bsum    = (int*)(base + BSUM_OFF);
        int*   list    = (int*)(base + LIST_OFF);

        convert_x_kernel<<<2048, 256, 0, stream>>>(x, xb, NNODE * C / 4);
        convert_w_kernel<<<(NREL * C * C + 255) / 256, 256, 0, stream>>>(w, wtb);

        hipMemsetAsync(count, 0, NNODE * sizeof(int), stream);
        hist_kernel<<<(NENT + 255) / 256, 256, 0, stream>>>(tgt, count);
        scan1_kernel<<<NB_SCAN, 256, 0, stream>>>(count, bsum);
        scan2_kernel<<<1, 512, 0, stream>>>(bsum);
        scan3_kernel<<<NB_SCAN, 256, 0, stream>>>(count, bsum, offsets, cursor);
        fill_kernel<<<(NENT + 255) / 256, 256, 0, stream>>>(tgt, cursor, list);

        dim3 grid(NTILE, NREL);
        fused_gather_gemm_kernel<<<grid, 512, 0, stream>>>(xb, ptr, idx, wtb, P);

        out_gather_kernel<<<(NNODE + 3) / 4, 256, 0, stream>>>(P, offsets, count, list, out);
    } else {
        hipMemsetAsync(out, 0, (size_t)NNODE * C * sizeof(float), stream);
        dim3 grid(NTILE, NREL);
        rgcn_fused_kernel<<<grid, 256, 0, stream>>>(x, w, ptr, idx, tgt, out);
    }
}